// Round 9
// baseline (272.079 us; speedup 1.0000x reference)
//
#include <hip/hip_runtime.h>
#include <math.h>

#define B_ 16
#define S_ 2048
#define DM_ 64
#define HD_ 1024

typedef float floatx4 __attribute__((ext_vector_type(4)));
typedef short bf16x8 __attribute__((ext_vector_type(8)));
typedef unsigned short ushort4v __attribute__((ext_vector_type(4)));
typedef unsigned short ushort8v __attribute__((ext_vector_type(8)));

// ---------------------------------------------------------------------------
// logits = x M x^T (M = Wq Wk^T), out = softmax(mask(logits/4)) @ (P x) @ Wv
//
// R8 (resubmit after container failure; kernel re-audited, unchanged):
// barrier-free main loop via swapped QK (S^T = mfma(A=x_keys, B=y^T)).
//   * QK swapped: A-frags = x key rows (per-lane 16B global loads from xh/xl,
//     batch-issued at tile top); B-frags = hoisted y regs (bit-identical).
//   * PX B-frags = per-lane 16B global loads from xTh, issued under softmax.
//   * NO x LDS staging, NO main-loop barriers. Waves drift freely.
//   * Softmax lane-local: lane owns q-row lm -> in-lane tree + 2 shfl_xor
//     (was 16 shfl); m/l scalar; alpha redistributed via 4 shfl for U rescale.
//   * exp2-domain softmax (0.25/ln2 folded; ==0 / -9e15 semantics preserved).
//   * P keeps wave-private LDS round-trip (same-wave lgkmcnt, no barrier).
//   * LDS 73.7KB -> 18.4KB (P overlays y; merge scratch/Un overlay all).
// Precision identical products to R7 (QK 3-term, PX 1-term): absmax ~0.031.
// ws (shorts): Mfh[4096] Mfl[4096] Wfh[65536] Wfl[65536]
//              xh[2M]@139264 xl@+2M xTh@+4M   (~12.9 MB)
// ---------------------------------------------------------------------------

__device__ __forceinline__ unsigned short bf_hi(float f) {
    return (unsigned short)((__float_as_uint(f) + 0x8000u) >> 16);   // RNE-ish
}
__device__ __forceinline__ float bf_f(unsigned short h) {
    return __uint_as_float((unsigned)h << 16);
}
__device__ __forceinline__ void cvt4(floatx4 v, ushort4v& h, ushort4v& l) {
    h[0] = bf_hi(v.x); l[0] = bf_hi(v.x - bf_f(h[0]));
    h[1] = bf_hi(v.y); l[1] = bf_hi(v.y - bf_f(h[1]));
    h[2] = bf_hi(v.z); l[2] = bf_hi(v.z - bf_f(h[2]));
    h[3] = bf_hi(v.w); l[3] = bf_hi(v.w - bf_f(h[3]));
}

#define MFMA(a, b, c) __builtin_amdgcn_mfma_f32_16x16x32_bf16((a), (b), (c), 0, 0, 0)

// frag-linear index for a B operand element (k, col):
//   idx = ((ct*2+kc)*64 + 16*lg+lm)*8 + j
__device__ __forceinline__ int fragidx(int k, int col) {
    return (((col >> 4) * 2 + (k >> 5)) * 64 + ((k >> 3) & 3) * 16 + (col & 15)) * 8
           + (k & 7);
}

// K1: prep (unchanged from R7, verified).
//   bid 0..15  : M = Wq Wk^T -> frag-linear split bf16
//   bid 16..19 : Wv -> frag-linear split bf16
//   bid 20..531: x -> xh/xl (row-major) + xTh (d-major, hi only)
__global__ __launch_bounds__(256) void k_prep(
        const float* __restrict__ x, const float* __restrict__ W,
        unsigned short* __restrict__ ws) {
    unsigned short* Mfh = ws;
    unsigned short* Mfl = ws + 4096;
    unsigned short* Wfh = ws + 8192;
    unsigned short* Wfl = ws + 73728;
    unsigned short* xh  = ws + 139264;
    unsigned short* xl  = xh + 2097152;
    unsigned short* xTh = xl + 2097152;
    const int bid = blockIdx.x, t = threadIdx.x;
    if (bid < 16) {
        const int d = bid * 4 + (t >> 6);
        const int e = t & 63;
        const floatx4* wq = (const floatx4*)(W + (size_t)d * 3072);
        const floatx4* wk = (const floatx4*)(W + (size_t)e * 3072 + 1024);
        floatx4 a = {0.f, 0.f, 0.f, 0.f};
#pragma unroll 4
        for (int j = 0; j < 256; ++j) {
            floatx4 qv = wq[j], kv = wk[j];
            a.x = fmaf(qv.x, kv.x, a.x);
            a.y = fmaf(qv.y, kv.y, a.y);
            a.z = fmaf(qv.z, kv.z, a.z);
            a.w = fmaf(qv.w, kv.w, a.w);
        }
        const float v = (a.x + a.y) + (a.z + a.w);
        const int idx = fragidx(d, e);
        const unsigned short hv = bf_hi(v);
        Mfh[idx] = hv;
        Mfl[idx] = bf_hi(v - bf_f(hv));
    } else if (bid < 20) {
        const int col = (bid - 16) * 256 + t;
#pragma unroll 8
        for (int k = 0; k < 64; ++k) {
            const float v = W[(size_t)k * 3072 + 2048 + col];
            const int idx = fragidx(k, col);
            const unsigned short hv = bf_hi(v);
            Wfh[idx] = hv;
            Wfl[idx] = bf_hi(v - bf_f(hv));
        }
    } else {
        const int xbid = bid - 20;              // 0..511
        const int bb = xbid >> 5, rb = xbid & 31;
        const int kg = t >> 4, dc = t & 15;     // 4 rows x 4 cols per thread
        const size_t r0 = (size_t)bb * S_ + rb * 64;
        const float* sp = x + (r0 + kg * 4) * 64 + dc * 4;
        floatx4 v0 = *(const floatx4*)(sp);
        floatx4 v1 = *(const floatx4*)(sp + 64);
        floatx4 v2 = *(const floatx4*)(sp + 128);
        floatx4 v3 = *(const floatx4*)(sp + 192);
        ushort4v h0, l0, h1, l1, h2, l2, h3, l3;
        cvt4(v0, h0, l0); cvt4(v1, h1, l1);
        cvt4(v2, h2, l2); cvt4(v3, h3, l3);
        const size_t ro = (r0 + kg * 4) * 64 + dc * 4;
        *(ushort4v*)(xh + ro)       = h0;
        *(ushort4v*)(xh + ro + 64)  = h1;
        *(ushort4v*)(xh + ro + 128) = h2;
        *(ushort4v*)(xh + ro + 192) = h3;
        *(ushort4v*)(xl + ro)       = l0;
        *(ushort4v*)(xl + ro + 64)  = l1;
        *(ushort4v*)(xl + ro + 128) = l2;
        *(ushort4v*)(xl + ro + 192) = l3;
#pragma unroll
        for (int e = 0; e < 4; ++e) {
            ushort4v th = {h0[e], h1[e], h2[e], h3[e]};   // keys 4kg..+3 @ d
            const size_t to = ((size_t)bb * 64 + dc * 4 + e) * 2048 + rb * 64 + kg * 4;
            *(ushort4v*)(xTh + to) = th;
        }
    }
}

// K2: fused y-GEMM + barrier-free flash attention + out-GEMM.
// 512 thr = 2 split-K halves of 4 waves; wave w (in half) owns q rows 16w..+15.
// Lane (lm,lg): owns q-row lm of its wave-strip for softmax state;
// S^T C-layout: lane holds S[key=16kb+4lg+r][q=lm].
__global__ __launch_bounds__(512, 4) void k_fused(
        const unsigned short* __restrict__ wsf, float* __restrict__ out) {
    // 18,432 B total. Phases: {yh@0, yl@4608} -> P 8x1152 @0 (overlay after
    // hoist) -> merge: scratch floats 0..4223 -> {Unh@0, Unl@4608}.
    __shared__ __align__(16) unsigned short sm[9216];

    const int tid  = threadIdx.x;
    const int h    = tid >> 8;
    const int lt   = tid & 255;
    const int w    = lt >> 6;            // wave in half 0..3
    const int wid  = tid >> 6;           // wave in block 0..7
    const int lane = tid & 63;
    const int lm   = lane & 15;
    const int lg   = lane >> 4;

    // bid remap: first 256 heavy (qt 0..15), second 256 light (qt 31..16).
    const int bi = blockIdx.x;
    int qt, bb;
    if (bi < 256) { qt = bi >> 4;                bb = bi & 15; }
    else          { qt = 31 - ((bi - 256) >> 4); bb = (bi - 256) & 15; }
    const int q0 = qt * 64;
    const int T  = 32 - qt;
    const int nA = (T + 1) >> 1;
    const int nOwn = h ? (T - nA) : nA;
    const int kt0  = q0 + (h ? nA * 64 : 0);

    unsigned short* yh = sm;
    unsigned short* yl = sm + 4608;
    unsigned short* Pw = sm + wid * 1152;   // per-wave P [16 q][72], overlays y

    const unsigned short* Mfh = wsf;
    const unsigned short* Mfl = wsf + 4096;
    const unsigned short* Wfh = wsf + 8192;
    const unsigned short* Wfl = wsf + 73728;
    const unsigned short* xh  = wsf + 139264;
    const unsigned short* xl  = xh + 2097152;
    const unsigned short* xTh = xl + 2097152;

    // ---- y prologue: y = xq @ M, 3-term, all 8 waves (R7 verified) ----
    {
        const int rt = wid & 3;
        const int cp = wid >> 2;
        bf16x8 axh[2], axl[2];
#pragma unroll
        for (int kc = 0; kc < 2; ++kc) {
            const size_t off =
                ((size_t)bb * S_ + q0 + 16 * rt + lm) * 64 + 32 * kc + 8 * lg;
            axh[kc] = *(const bf16x8*)(xh + off);
            axl[kc] = *(const bf16x8*)(xl + off);
        }
#pragma unroll
        for (int cc = 0; cc < 2; ++cc) {
            const int ct = cp * 2 + cc;
            floatx4 yC = {0.f, 0.f, 0.f, 0.f};
#pragma unroll
            for (int kc = 0; kc < 2; ++kc) {
                bf16x8 bh = *(const bf16x8*)(Mfh + ((ct * 2 + kc) * 64 + lane) * 8);
                bf16x8 bl = *(const bf16x8*)(Mfl + ((ct * 2 + kc) * 64 + lane) * 8);
                yC = MFMA(axh[kc], bh, yC);
                yC = MFMA(axh[kc], bl, yC);
                yC = MFMA(axl[kc], bh, yC);
            }
#pragma unroll
            for (int r = 0; r < 4; ++r) {
                const float vv = yC[r];
                const unsigned short hv = bf_hi(vv);
                const int o = (16 * rt + 4 * lg + r) * 72 + ct * 16 + lm;
                yh[o] = hv;
                yl[o] = bf_hi(vv - bf_f(hv));
            }
        }
    }
    __syncthreads();   // y visible

    // hoist y frags (loop-invariant; serve as MFMA *B* operands after swap)
    bf16x8 aqh[2], aql[2];
#pragma unroll
    for (int kc = 0; kc < 2; ++kc) {
        const int off = (16 * w + lm) * 72 + 32 * kc + 8 * lg;
        aqh[kc] = *(const bf16x8*)(yh + off);
        aql[kc] = *(const bf16x8*)(yl + off);
    }
    __syncthreads();   // y dead everywhere -> P may overlay it

    const float C2 = 0.36067376022224085f;   // 0.25 / ln2 (exp2 domain)
    const int ig = q0 + 16 * w + lm;         // this lane's q-row global index

    floatx4 U[4];      // U[c][r] = U[q=4lg+r][d=lm+16c]
    float m = -INFINITY, lsum = 0.f;         // per-lane state for q-row lm
#pragma unroll
    for (int c = 0; c < 4; ++c) U[c] = (floatx4){0.f, 0.f, 0.f, 0.f};

    for (int t = 0; t < nOwn; ++t) {
        const int kt = kt0 + t * 64;

        // ---- batch-issue QK A-frags (x key rows), 16 x b128 global ----
        bf16x8 kxh[4][2], kxl[4][2];
#pragma unroll
        for (int kb = 0; kb < 4; ++kb)
#pragma unroll
            for (int kc = 0; kc < 2; ++kc) {
                const size_t o =
                    ((size_t)bb * S_ + kt + 16 * kb + lm) * 64 + 32 * kc + 8 * lg;
                kxh[kb][kc] = *(const bf16x8*)(xh + o);
                kxl[kb][kc] = *(const bf16x8*)(xl + o);
            }

        // ---- QK swapped: Sc[kb] = S^T[key-tile kb][q], 3-term, 24 mfma ----
        floatx4 Sc[4] = {{0.f,0.f,0.f,0.f},{0.f,0.f,0.f,0.f},
                         {0.f,0.f,0.f,0.f},{0.f,0.f,0.f,0.f}};
#pragma unroll
        for (int kb = 0; kb < 4; ++kb)
#pragma unroll
            for (int kc = 0; kc < 2; ++kc) {
                Sc[kb] = MFMA(kxh[kb][kc], aqh[kc], Sc[kb]);
                Sc[kb] = MFMA(kxl[kb][kc], aqh[kc], Sc[kb]);
                Sc[kb] = MFMA(kxh[kb][kc], aql[kc], Sc[kb]);
            }

        // ---- issue PX B-frags now (x^T rows); latency hides under softmax ----
        bf16x8 bx[4][2];
#pragma unroll
        for (int c = 0; c < 4; ++c)
#pragma unroll
            for (int kc = 0; kc < 2; ++kc)
                bx[c][kc] = *(const bf16x8*)(
                    xTh + ((size_t)bb * 64 + lm + 16 * c) * 2048
                        + kt + 32 * kc + 8 * lg);

        // ---- lane-local mask + softmax (q-row lm; keys 16kb+4lg+r) ----
        const bool diag = (kt == q0);   // wave-uniform; half A tile 0 only
        float sv[4][4];
        float rmax = -INFINITY;
#pragma unroll
        for (int kb = 0; kb < 4; ++kb)
#pragma unroll
            for (int r = 0; r < 4; ++r) {
                float v = Sc[kb][r] * C2;
                bool dead = (v == 0.0f);                    // faithful ==0 quirk
                if (diag) dead = dead || ((kt + 16 * kb + 4 * lg + r) < ig);
                if (dead) v = -9.0e15f;
                sv[kb][r] = v;
                rmax = fmaxf(rmax, v);
            }
        rmax = fmaxf(rmax, __shfl_xor(rmax, 16));
        rmax = fmaxf(rmax, __shfl_xor(rmax, 32));
        const float mnew = fmaxf(m, rmax);
        const float alpha = exp2f(m - mnew);                // first tile: 0
        float ps = 0.f;
#pragma unroll
        for (int kb = 0; kb < 4; ++kb)
#pragma unroll
            for (int r = 0; r < 4; ++r) {
                const float pv = exp2f(sv[kb][r] - mnew);
                sv[kb][r] = pv;
                ps += pv;
            }
        m = mnew;
        lsum = lsum * alpha + ps;       // lg-partial; cross-lg reduced at end

        // P -> wave-private LDS: Pw[q=lm][key]; same-wave RAW via lgkmcnt
#pragma unroll
        for (int kb = 0; kb < 4; ++kb)
#pragma unroll
            for (int r = 0; r < 4; ++r)
                Pw[lm * 72 + 16 * kb + 4 * lg + r] = bf_hi(sv[kb][r]);

        // alpha redistribution to (lg,r) q-indexing, then U rescale
        floatx4 av;
#pragma unroll
        for (int r = 0; r < 4; ++r) av[r] = __shfl(alpha, 4 * lg + r);
#pragma unroll
        for (int c = 0; c < 4; ++c) U[c] *= av;

        // ---- PX: U[q][d] += P[q][key] x[key][d], 1-term, 8 mfma ----
#pragma unroll
        for (int kc = 0; kc < 2; ++kc) {
            bf16x8 ap = *(const bf16x8*)(Pw + lm * 72 + 32 * kc + 8 * lg);
#pragma unroll
            for (int c = 0; c < 4; ++c)
                U[c] = MFMA(ap, bx[c][kc], U[c]);
        }
    }

    // ---- finalize per-half l: cross-lg reduce (2 shfl) ----
    float ls = lsum;
    ls += __shfl_xor(ls, 16);
    ls += __shfl_xor(ls, 32);

    // ---- merge halves via LDS scratch (P dead) ----
    __syncthreads();
    float* sc  = (float*)sm;            // U partials: lt*16, 4096 floats
    float* mlB = sc + 4096;             // m[64 q], l[64 q] of half B
    if (h == 1) {
        float* bp = sc + lt * 16;
#pragma unroll
        for (int c = 0; c < 4; ++c) *(floatx4*)(bp + 4 * c) = U[c];
        if (lg == 0) {
            mlB[16 * w + lm]      = m;
            mlB[64 + 16 * w + lm] = ls;
        }
    }
    __syncthreads();
    floatx4 o4[4];
    if (h == 0) {
        const float* bp = sc + lt * 16;
        floatx4 UB[4];
#pragma unroll
        for (int c = 0; c < 4; ++c) UB[c] = *(const floatx4*)(bp + 4 * c);
        const float mB = mlB[16 * w + lm];
        const float lB = mlB[64 + 16 * w + lm];
        const float mT  = fmaxf(m, mB);          // m finite (A has tile 0)
        const float eA  = exp2f(m - mT);
        const float eB  = exp2f(mB - mT);        // empty B: exp2(-inf)=0
        const float inv = 1.0f / (ls * eA + lB * eB);
        float eAr[4], eBr[4], ivr[4];
#pragma unroll
        for (int r = 0; r < 4; ++r) {
            eAr[r] = __shfl(eA, 4 * lg + r);
            eBr[r] = __shfl(eB, 4 * lg + r);
            ivr[r] = __shfl(inv, 4 * lg + r);
        }
#pragma unroll
        for (int c = 0; c < 4; ++c)
#pragma unroll
            for (int r = 0; r < 4; ++r)
                o4[c][r] = (U[c][r] * eAr[r] + UB[c][r] * eBr[r]) * ivr[r];
    }
    __syncthreads();   // all scratch reads done; Un may overlay
    unsigned short* Unh = sm;
    unsigned short* Unl = sm + 4608;
    if (h == 0) {
#pragma unroll
        for (int c = 0; c < 4; ++c)
#pragma unroll
            for (int r = 0; r < 4; ++r) {
                const float o = o4[c][r];
                const unsigned short hv = bf_hi(o);
                const int oo = (16 * w + 4 * lg + r) * 72 + lm + 16 * c;
                Unh[oo] = hv;
                Unl[oo] = bf_hi(o - bf_f(hv));
            }
    }
    __syncthreads();   // Un visible

    // ---- out-GEMM: out = Un @ Wv, 3-term, all 8 waves (R7 verified) ----
    bf16x8 Ah[4][2], Al[4][2];
#pragma unroll
    for (int rt = 0; rt < 4; ++rt)
#pragma unroll
        for (int kc = 0; kc < 2; ++kc) {
            const int off = (16 * rt + lm) * 72 + 32 * kc + 8 * lg;
            Ah[rt][kc] = *(const bf16x8*)(Unh + off);
            Al[rt][kc] = *(const bf16x8*)(Unl + off);
        }
    const size_t orow0 = (size_t)bb * S_ + q0;
#pragma unroll
    for (int ctl = 0; ctl < 8; ++ctl) {
        const int ct = wid * 8 + ctl;
        bf16x8 Bh0 = *(const bf16x8*)(Wfh + ((ct * 2 + 0) * 64 + lane) * 8);
        bf16x8 Bl0 = *(const bf16x8*)(Wfl + ((ct * 2 + 0) * 64 + lane) * 8);
        bf16x8 Bh1 = *(const bf16x8*)(Wfh + ((ct * 2 + 1) * 64 + lane) * 8);
        bf16x8 Bl1 = *(const bf16x8*)(Wfl + ((ct * 2 + 1) * 64 + lane) * 8);
#pragma unroll
        for (int rt = 0; rt < 4; ++rt) {
            floatx4 C = {0.f, 0.f, 0.f, 0.f};
            C = MFMA(Ah[rt][0], Bh0, C);
            C = MFMA(Ah[rt][0], Bl0, C);
            C = MFMA(Al[rt][0], Bh0, C);
            C = MFMA(Ah[rt][1], Bh1, C);
            C = MFMA(Ah[rt][1], Bl1, C);
            C = MFMA(Al[rt][1], Bh1, C);
#pragma unroll
            for (int r = 0; r < 4; ++r)
                out[(orow0 + 16 * rt + 4 * lg + r) * HD_ + ct * 16 + lm] = C[r];
        }
    }
}

extern "C" void kernel_launch(void* const* d_in, const int* in_sizes, int n_in,
                              void* d_out, int out_size, void* d_ws, size_t ws_size,
                              hipStream_t stream) {
    const float* x = (const float*)d_in[0];
    const float* W = (const float*)d_in[1];
    unsigned short* wsf = (unsigned short*)d_ws;   // ~12.9 MB used

    k_prep <<<dim3(532), 256, 0, stream>>>(x, W, wsf);
    k_fused<<<dim3(512), 512, 0, stream>>>(wsf, (float*)d_out);
}